// Round 5
// baseline (335.484 us; speedup 1.0000x reference)
//
#include <hip/hip_runtime.h>

// ---------------------------------------------------------------------------
// 2-layer GCN + linear head on MI355X.
// R3: counting-sort CSR build (coarse radix by dst>>9, per-bucket LDS build).
// R4: agg_kernel software-pipelined (8 gathers in flight).
// R5: register-blocked GEMM — 8x8 outputs/thread, 128-thr blocks, X staged
//     TRANSPOSED in LDS (8 row-vals = 2x ds_read_b128). 0.75 LDS-cyc/FMA vs
//     4.5 before (old gemm was LDS-throughput-bound at ~45us each).
//     zero_i32 kernel replaced by hipMemsetAsync.
// ---------------------------------------------------------------------------

#define NODE_SHIFT 9
#define NODES_PER_BKT 512

// Per-block LDS histogram of dst>>NODE_SHIFT over a contiguous chunk.
__global__ __launch_bounds__(256) void coarse_hist_kernel(const int* __restrict__ dst, int E,
                                                          int* __restrict__ bkt_cnt,
                                                          int K1, int CHK) {
    __shared__ int lcnt[256];
    const int tid = threadIdx.x;
    const int start = blockIdx.x * CHK;
    const int end = min(E, start + CHK);
    for (int k = tid; k < K1; k += 256) lcnt[k] = 0;
    __syncthreads();
    for (int i = start + tid; i < end; i += 256)
        atomicAdd(&lcnt[dst[i] >> NODE_SHIFT], 1);
    __syncthreads();
    for (int k = tid; k < K1; k += 256)
        if (lcnt[k]) atomicAdd(&bkt_cnt[k], lcnt[k]);
}

// Exclusive scan of K1 (<=256) bucket counts. One wave, 4 entries/lane.
__global__ __launch_bounds__(64) void bucket_scan_kernel(const int* __restrict__ bkt_cnt,
                                                         int* __restrict__ bkt_start,
                                                         int* __restrict__ bkt_cursor,
                                                         int K1, int E) {
    const int lane = threadIdx.x;
    int v[4];
    int s = 0;
#pragma unroll
    for (int j = 0; j < 4; j++) {
        int idx = lane * 4 + j;
        v[j] = (idx < K1) ? bkt_cnt[idx] : 0;
        s += v[j];
    }
    int inc = s;
#pragma unroll
    for (int o = 1; o < 64; o <<= 1) {
        int t = __shfl_up(inc, o, 64);
        if (lane >= o) inc += t;
    }
    int run = inc - s;  // exclusive
#pragma unroll
    for (int j = 0; j < 4; j++) {
        int idx = lane * 4 + j;
        if (idx < K1) { bkt_start[idx] = run; bkt_cursor[idx] = run; }
        run += v[j];
    }
    if (lane == 0) bkt_start[K1] = E;
}

// Partition edges into coarse buckets: LDS hist -> range reservation -> write.
__global__ __launch_bounds__(256) void partition_kernel(const int* __restrict__ src,
                                                        const int* __restrict__ dst, int E,
                                                        int* __restrict__ bkt_cursor,
                                                        int2* __restrict__ staging,
                                                        int K1, int CHK) {
    __shared__ int lcnt[256];
    __shared__ int lcur[256];
    const int tid = threadIdx.x;
    const int start = blockIdx.x * CHK;
    const int end = min(E, start + CHK);
    for (int k = tid; k < K1; k += 256) lcnt[k] = 0;
    __syncthreads();
    for (int i = start + tid; i < end; i += 256)
        atomicAdd(&lcnt[dst[i] >> NODE_SHIFT], 1);
    __syncthreads();
    for (int k = tid; k < K1; k += 256) {
        int c = lcnt[k];
        lcur[k] = c ? atomicAdd(&bkt_cursor[k], c) : 0;
    }
    __syncthreads();
    for (int i = start + tid; i < end; i += 256) {
        int d = dst[i];
        int s = src[i];
        int pos = atomicAdd(&lcur[d >> NODE_SHIFT], 1);
        staging[pos] = make_int2(d, s);
    }
}

// One block per bucket: LDS degree count -> scan -> offs/dinv -> final CSR.
__global__ __launch_bounds__(256) void bucket_build_kernel(const int2* __restrict__ staging,
                                                           const int* __restrict__ bkt_start,
                                                           float* __restrict__ dinv,
                                                           int* __restrict__ offs,
                                                           int* __restrict__ csr_src,
                                                           int N, int E) {
    __shared__ int cnt[NODES_PER_BKT];
    __shared__ int wsum[4];
    const int tid = threadIdx.x;
    const int node0 = blockIdx.x * NODES_PER_BKT;
    const int estart = bkt_start[blockIdx.x];
    const int eend = bkt_start[blockIdx.x + 1];

    cnt[tid] = 0;
    cnt[tid + 256] = 0;
    __syncthreads();
    for (int e = estart + tid; e < eend; e += 256)
        atomicAdd(&cnt[staging[e].x - node0], 1);
    __syncthreads();

    const int lane = tid & 63;
    const int wave = tid >> 6;
    int c0 = cnt[2 * tid];
    int c1 = cnt[2 * tid + 1];
    int s = c0 + c1;
    int inc = s;
#pragma unroll
    for (int o = 1; o < 64; o <<= 1) {
        int t = __shfl_up(inc, o, 64);
        if (lane >= o) inc += t;
    }
    if (lane == 63) wsum[wave] = inc;
    __syncthreads();
    int wpre = 0;
#pragma unroll
    for (int w = 0; w < 4; w++) wpre += (w < wave) ? wsum[w] : 0;
    const int excl = wpre + inc - s;

    const int n0 = node0 + 2 * tid;
    const int n1 = n0 + 1;
    const int p0 = estart + excl;
    const int p1 = p0 + c0;
    __syncthreads();  // cnt reuse as cursor
    if (n0 < N) {
        offs[n0] = p0;
        dinv[n0] = rsqrtf((float)c0 + 1.0f);
        cnt[2 * tid] = p0;
    }
    if (n1 < N) {
        offs[n1] = p1;
        dinv[n1] = rsqrtf((float)c1 + 1.0f);
        cnt[2 * tid + 1] = p1;
    }
    __syncthreads();
    for (int e = estart + tid; e < eend; e += 256) {
        int2 r = staging[e];
        int pos = atomicAdd(&cnt[r.x - node0], 1);
        csr_src[pos] = r.y;
    }
    if (blockIdx.x == 0 && tid == 0) offs[N] = E;
}

// Y[N,OUTC] = (X[N,64] @ W[64,OUTC]) * (SCALE ? dinv[row] : 1) (+ bias)
// R5: 128 threads/block, 8x8 outputs/thread, X transposed in LDS.
template <int OUTC, bool BIAS, bool SCALE>
__global__ __launch_bounds__(128) void gemm_kernel(const float* __restrict__ X,
                                                   const float* __restrict__ W,
                                                   const float* __restrict__ bias,
                                                   const float* __restrict__ dinv,
                                                   float* __restrict__ Y, int N) {
    constexpr int CG = OUTC / 8;   // col groups (8 cols each)
    constexpr int R = (128 / CG) * 8;  // rows per block (64-out: 128; 32-out: 256)
    __shared__ float Ws[64 * OUTC];
    __shared__ float Xt[64 * R];   // transposed: Xt[k*R + r]

    const int tid = threadIdx.x;
    const int row0 = blockIdx.x * R;

    for (int l = tid; l < 64 * OUTC / 4; l += 128)
        ((float4*)Ws)[l] = ((const float4*)W)[l];

    for (int r = tid; r < R; r += 128) {
        const int row = row0 + r;
        if (row < N) {
            const float4* xr = (const float4*)(X + (long)row * 64);
#pragma unroll
            for (int kq = 0; kq < 16; kq++) {
                float4 v = xr[kq];
                Xt[(4 * kq + 0) * R + r] = v.x;
                Xt[(4 * kq + 1) * R + r] = v.y;
                Xt[(4 * kq + 2) * R + r] = v.z;
                Xt[(4 * kq + 3) * R + r] = v.w;
            }
        } else {
#pragma unroll
            for (int kq = 0; kq < 16; kq++) {
                Xt[(4 * kq + 0) * R + r] = 0.f;
                Xt[(4 * kq + 1) * R + r] = 0.f;
                Xt[(4 * kq + 2) * R + r] = 0.f;
                Xt[(4 * kq + 3) * R + r] = 0.f;
            }
        }
    }
    __syncthreads();

    const int cg = tid % CG;
    const int rg = tid / CG;
    const int c0 = cg * 8;
    const int r0 = rg * 8;

    float acc[8][8];
#pragma unroll
    for (int i = 0; i < 8; i++)
#pragma unroll
        for (int j = 0; j < 8; j++) acc[i][j] = 0.f;

#pragma unroll 8
    for (int k = 0; k < 64; k++) {
        const float4 xa = *(const float4*)&Xt[k * R + r0];
        const float4 xb = *(const float4*)&Xt[k * R + r0 + 4];
        const float4 wa = *(const float4*)&Ws[k * OUTC + c0];
        const float4 wb = *(const float4*)&Ws[k * OUTC + c0 + 4];
        const float xv[8] = {xa.x, xa.y, xa.z, xa.w, xb.x, xb.y, xb.z, xb.w};
        const float wv[8] = {wa.x, wa.y, wa.z, wa.w, wb.x, wb.y, wb.z, wb.w};
#pragma unroll
        for (int i = 0; i < 8; i++)
#pragma unroll
            for (int j = 0; j < 8; j++)
                acc[i][j] += xv[i] * wv[j];
    }

#pragma unroll
    for (int i = 0; i < 8; i++) {
        const int row = row0 + r0 + i;
        if (row < N) {
            const float sc = SCALE ? dinv[row] : 1.f;
            float4 o0 = make_float4(acc[i][0] * sc, acc[i][1] * sc,
                                    acc[i][2] * sc, acc[i][3] * sc);
            float4 o1 = make_float4(acc[i][4] * sc, acc[i][5] * sc,
                                    acc[i][6] * sc, acc[i][7] * sc);
            if (BIAS) {
                const float4 ba = *(const float4*)&bias[c0];
                const float4 bb = *(const float4*)&bias[c0 + 4];
                o0.x += ba.x; o0.y += ba.y; o0.z += ba.z; o0.w += ba.w;
                o1.x += bb.x; o1.y += bb.y; o1.z += bb.z; o1.w += bb.w;
            }
            *(float4*)&Y[(long)row * OUTC + c0] = o0;
            *(float4*)&Y[(long)row * OUTC + c0 + 4] = o1;
        }
    }
}

// out[i] = relu( dinv_i * (sum_e T'[src_e] + T'[i]) + b ),  T' pre-scaled by dinv_row.
// 16 lanes/node, float4/lane. 8 gathers in flight, pipelined index loads.
template <bool RELU>
__global__ __launch_bounds__(256) void agg_kernel(const float* __restrict__ T,
                                                  const int* __restrict__ offs,
                                                  const int* __restrict__ csr_src,
                                                  const float* __restrict__ dinv,
                                                  const float* __restrict__ bias,
                                                  float* __restrict__ Y, int N) {
    const int tid = threadIdx.x;
    const int node = blockIdx.x * 16 + (tid >> 4);
    const int l16 = tid & 15;
    if (node >= N) return;

    const int start = offs[node];
    const int n_edges = offs[node + 1] - start;
    const int* ep = csr_src + start;
    const int fo = l16 * 4;

    float4 acc = make_float4(0.f, 0.f, 0.f, 0.f);

    int s[8];
    int e = 0;
    if (n_edges >= 8) {
#pragma unroll
        for (int j = 0; j < 8; j++) s[j] = ep[j];
        while (true) {
            float4 h[8];
#pragma unroll
            for (int j = 0; j < 8; j++)
                h[j] = *(const float4*)&T[(long)s[j] * 64 + fo];
            const int next = e + 8;
            const bool more = (next + 8 <= n_edges);
            if (more) {
#pragma unroll
                for (int j = 0; j < 8; j++) s[j] = ep[next + j];
            }
#pragma unroll
            for (int j = 0; j < 8; j++) {
                acc.x += h[j].x;
                acc.y += h[j].y;
                acc.z += h[j].z;
                acc.w += h[j].w;
            }
            e = next;
            if (!more) break;
        }
    }
    if (e + 4 <= n_edges) {
        int s4[4];
#pragma unroll
        for (int j = 0; j < 4; j++) s4[j] = ep[e + j];
        float4 h[4];
#pragma unroll
        for (int j = 0; j < 4; j++)
            h[j] = *(const float4*)&T[(long)s4[j] * 64 + fo];
#pragma unroll
        for (int j = 0; j < 4; j++) {
            acc.x += h[j].x;
            acc.y += h[j].y;
            acc.z += h[j].z;
            acc.w += h[j].w;
        }
        e += 4;
    }
    for (; e < n_edges; e++) {
        const float4 hv = *(const float4*)&T[(long)ep[e] * 64 + fo];
        acc.x += hv.x;
        acc.y += hv.y;
        acc.z += hv.z;
        acc.w += hv.w;
    }

    const float di = dinv[node];
    const float4 self = *(const float4*)&T[(long)node * 64 + fo];
    const float4 b4 = *(const float4*)&bias[fo];
    float4 o;
    o.x = di * (acc.x + self.x) + b4.x;
    o.y = di * (acc.y + self.y) + b4.y;
    o.z = di * (acc.z + self.z) + b4.z;
    o.w = di * (acc.w + self.w) + b4.w;
    if (RELU) {
        o.x = fmaxf(o.x, 0.f);
        o.y = fmaxf(o.y, 0.f);
        o.z = fmaxf(o.z, 0.f);
        o.w = fmaxf(o.w, 0.f);
    }
    *(float4*)&Y[(long)node * 64 + fo] = o;
}

extern "C" void kernel_launch(void* const* d_in, const int* in_sizes, int n_in,
                              void* d_out, int out_size, void* d_ws, size_t ws_size,
                              hipStream_t stream) {
    const float* x  = (const float*)d_in[0];
    const int*   ei = (const int*)d_in[1];
    const float* W1 = (const float*)d_in[2];
    const float* b1 = (const float*)d_in[3];
    const float* W2 = (const float*)d_in[4];
    const float* b2 = (const float*)d_in[5];
    const float* Wf = (const float*)d_in[6];
    const float* bf = (const float*)d_in[7];

    const int N = in_sizes[0] / 64;
    const int E = in_sizes[1] / 2;
    const int* src = ei;
    const int* dst = ei + E;
    const int K1 = (N + NODES_PER_BKT - 1) / NODES_PER_BKT;

    char* ws = (char*)d_ws;
    size_t off = 0;
    auto alloc = [&](size_t bytes) -> void* {
        void* p = ws + off;
        off = (off + bytes + 255) & ~(size_t)255;
        return p;
    };
    int*   bkt_cnt    = (int*)alloc(256 * 4);
    int*   bkt_start  = (int*)alloc(257 * 4);
    int*   bkt_cursor = (int*)alloc(256 * 4);
    float* dinv       = (float*)alloc((size_t)N * 4);
    int*   offs       = (int*)alloc((size_t)(N + 1) * 4);
    int*   csr_src    = (int*)alloc((size_t)E * 4);
    float* A          = (float*)alloc((size_t)N * 64 * 4);
    float* B          = (float*)alloc((size_t)N * 64 * 4);
    int2*  staging    = (int2*)A;  // dead before gemm1 writes A

    const int NB = 128;
    const int CHK = (E + NB - 1) / NB;

    // ---- CSR build: counting sort, no random scatter ----
    hipMemsetAsync(bkt_cnt, 0, (size_t)K1 * 4, stream);
    coarse_hist_kernel<<<NB, 256, 0, stream>>>(dst, E, bkt_cnt, K1, CHK);
    bucket_scan_kernel<<<1, 64, 0, stream>>>(bkt_cnt, bkt_start, bkt_cursor, K1, E);
    partition_kernel<<<NB, 256, 0, stream>>>(src, dst, E, bkt_cursor, staging, K1, CHK);
    bucket_build_kernel<<<K1, 256, 0, stream>>>(staging, bkt_start, dinv, offs, csr_src, N, E);

    // ---- layer 1 ----
    gemm_kernel<64, false, true><<<(N + 127) / 128, 128, 0, stream>>>(x, W1, nullptr, dinv, A, N);
    agg_kernel<true><<<(N + 15) / 16, 256, 0, stream>>>(A, offs, csr_src, dinv, b1, B, N);

    // ---- layer 2 ----
    gemm_kernel<64, false, true><<<(N + 127) / 128, 128, 0, stream>>>(B, W2, nullptr, dinv, A, N);
    agg_kernel<true><<<(N + 15) / 16, 256, 0, stream>>>(A, offs, csr_src, dinv, b2, B, N);

    // ---- head ----
    gemm_kernel<32, true, false><<<(N + 255) / 256, 128, 0, stream>>>(B, Wf, bf, nullptr, (float*)d_out, N);
}

// Round 6
// 310.864 us; speedup vs baseline: 1.0792x; 1.0792x over previous
//
#include <hip/hip_runtime.h>

// ---------------------------------------------------------------------------
// 2-layer GCN + linear head on MI355X.
// R3: counting-sort CSR build (coarse radix by dst>>9, per-bucket LDS build).
// R4: agg_kernel software-pipelined (8 gathers in flight).
// R6: gemm rewritten spill-safe: 256 thr, 8x4 (head 4x4) acc regs, unroll 4,
//     X transposed in LDS with +4w/32rows pad (conflict-free b128 reads).
//     (R5's 8x8/unroll-8 version spilled VGPRs -> neutral.)
//     Build parallelism: bucket_build 512-thr blocks; hist/partition 256 blocks.
// ---------------------------------------------------------------------------

#define NODE_SHIFT 9
#define NODES_PER_BKT 512

// Per-block LDS histogram of dst>>NODE_SHIFT over a contiguous chunk.
__global__ __launch_bounds__(256) void coarse_hist_kernel(const int* __restrict__ dst, int E,
                                                          int* __restrict__ bkt_cnt,
                                                          int K1, int CHK) {
    __shared__ int lcnt[256];
    const int tid = threadIdx.x;
    const int start = blockIdx.x * CHK;
    const int end = min(E, start + CHK);
    for (int k = tid; k < K1; k += 256) lcnt[k] = 0;
    __syncthreads();
    for (int i = start + tid; i < end; i += 256)
        atomicAdd(&lcnt[dst[i] >> NODE_SHIFT], 1);
    __syncthreads();
    for (int k = tid; k < K1; k += 256)
        if (lcnt[k]) atomicAdd(&bkt_cnt[k], lcnt[k]);
}

// Exclusive scan of K1 (<=256) bucket counts. One wave, 4 entries/lane.
__global__ __launch_bounds__(64) void bucket_scan_kernel(const int* __restrict__ bkt_cnt,
                                                         int* __restrict__ bkt_start,
                                                         int* __restrict__ bkt_cursor,
                                                         int K1, int E) {
    const int lane = threadIdx.x;
    int v[4];
    int s = 0;
#pragma unroll
    for (int j = 0; j < 4; j++) {
        int idx = lane * 4 + j;
        v[j] = (idx < K1) ? bkt_cnt[idx] : 0;
        s += v[j];
    }
    int inc = s;
#pragma unroll
    for (int o = 1; o < 64; o <<= 1) {
        int t = __shfl_up(inc, o, 64);
        if (lane >= o) inc += t;
    }
    int run = inc - s;  // exclusive
#pragma unroll
    for (int j = 0; j < 4; j++) {
        int idx = lane * 4 + j;
        if (idx < K1) { bkt_start[idx] = run; bkt_cursor[idx] = run; }
        run += v[j];
    }
    if (lane == 0) bkt_start[K1] = E;
}

// Partition edges into coarse buckets: LDS hist -> range reservation -> write.
__global__ __launch_bounds__(256) void partition_kernel(const int* __restrict__ src,
                                                        const int* __restrict__ dst, int E,
                                                        int* __restrict__ bkt_cursor,
                                                        int2* __restrict__ staging,
                                                        int K1, int CHK) {
    __shared__ int lcnt[256];
    __shared__ int lcur[256];
    const int tid = threadIdx.x;
    const int start = blockIdx.x * CHK;
    const int end = min(E, start + CHK);
    for (int k = tid; k < K1; k += 256) lcnt[k] = 0;
    __syncthreads();
    for (int i = start + tid; i < end; i += 256)
        atomicAdd(&lcnt[dst[i] >> NODE_SHIFT], 1);
    __syncthreads();
    for (int k = tid; k < K1; k += 256) {
        int c = lcnt[k];
        lcur[k] = c ? atomicAdd(&bkt_cursor[k], c) : 0;
    }
    __syncthreads();
    for (int i = start + tid; i < end; i += 256) {
        int d = dst[i];
        int s = src[i];
        int pos = atomicAdd(&lcur[d >> NODE_SHIFT], 1);
        staging[pos] = make_int2(d, s);
    }
}

// One 512-thr block per bucket: LDS degree count -> scan -> offs/dinv -> CSR.
__global__ __launch_bounds__(512) void bucket_build_kernel(const int2* __restrict__ staging,
                                                           const int* __restrict__ bkt_start,
                                                           float* __restrict__ dinv,
                                                           int* __restrict__ offs,
                                                           int* __restrict__ csr_src,
                                                           int N, int E) {
    __shared__ int cnt[NODES_PER_BKT];
    __shared__ int wsum[8];
    const int tid = threadIdx.x;
    const int node0 = blockIdx.x * NODES_PER_BKT;
    const int estart = bkt_start[blockIdx.x];
    const int eend = bkt_start[blockIdx.x + 1];

    cnt[tid] = 0;
    __syncthreads();
    for (int e = estart + tid; e < eend; e += 512)
        atomicAdd(&cnt[staging[e].x - node0], 1);
    __syncthreads();

    const int lane = tid & 63;
    const int wave = tid >> 6;
    const int c = cnt[tid];
    int inc = c;
#pragma unroll
    for (int o = 1; o < 64; o <<= 1) {
        int t = __shfl_up(inc, o, 64);
        if (lane >= o) inc += t;
    }
    if (lane == 63) wsum[wave] = inc;
    __syncthreads();
    int wpre = 0;
#pragma unroll
    for (int w = 0; w < 8; w++) wpre += (w < wave) ? wsum[w] : 0;
    const int p = estart + wpre + inc - c;  // exclusive within bucket

    const int node = node0 + tid;
    __syncthreads();  // cnt reuse as cursor
    if (node < N) {
        offs[node] = p;
        dinv[node] = rsqrtf((float)c + 1.0f);
    }
    cnt[tid] = p;
    __syncthreads();
    for (int e = estart + tid; e < eend; e += 512) {
        int2 r = staging[e];
        int pos = atomicAdd(&cnt[r.x - node0], 1);
        csr_src[pos] = r.y;
    }
    if (blockIdx.x == 0 && tid == 0) offs[N] = E;
}

// Y[N,OUTC] = (X[N,64] @ W[64,OUTC]) * (SCALE ? dinv[row] : 1) (+ bias)
// R6: 256 thr/block, RPT rows x 4 cols per thread, X transposed in LDS with
// +4 words per 32 rows pad -> conflict-free b128 reads. unroll 4, no spill.
template <int OUTC, int RPT, bool BIAS, bool SCALE>
__global__ __launch_bounds__(256) void gemm_kernel(const float* __restrict__ X,
                                                   const float* __restrict__ W,
                                                   const float* __restrict__ bias,
                                                   const float* __restrict__ dinv,
                                                   float* __restrict__ Y, int N) {
    constexpr int CG = OUTC / 4;         // col groups
    constexpr int RG = 256 / CG;         // row groups
    constexpr int R = RG * RPT;          // rows per block (128 for both configs)
    constexpr int RPAD = R + (R / 32) * 4;
    __shared__ float Ws[64 * OUTC];
    __shared__ float Xt[64 * RPAD];

    const int tid = threadIdx.x;
    const int row0 = blockIdx.x * R;

    for (int l = tid; l < 64 * OUTC / 4; l += 256)
        ((float4*)Ws)[l] = ((const float4*)W)[l];

    // stage X transposed: Xt[k*RPAD + r + (r>>5)*4]
    for (int l = tid; l < R * 16; l += 256) {
        const int r = l & (R - 1);
        const int kq = l >> 7;  // R == 128
        float4 v = make_float4(0.f, 0.f, 0.f, 0.f);
        const int row = row0 + r;
        if (row < N) v = ((const float4*)(X + (long)row * 64))[kq];
        const int rp = r + (r >> 5) * 4;
        Xt[(4 * kq + 0) * RPAD + rp] = v.x;
        Xt[(4 * kq + 1) * RPAD + rp] = v.y;
        Xt[(4 * kq + 2) * RPAD + rp] = v.z;
        Xt[(4 * kq + 3) * RPAD + rp] = v.w;
    }
    __syncthreads();

    const int cg = tid % CG;
    const int rg = tid / CG;
    const int c0 = cg * 4;
    const int r0 = rg * RPT;
    const int r0p = r0 + (r0 >> 5) * 4;

    float acc[RPT][4];
#pragma unroll
    for (int i = 0; i < RPT; i++)
#pragma unroll
        for (int j = 0; j < 4; j++) acc[i][j] = 0.f;

#pragma unroll 4
    for (int k = 0; k < 64; k++) {
        float xv[RPT];
        const float4 xa = *(const float4*)&Xt[k * RPAD + r0p];
        xv[0] = xa.x; xv[1] = xa.y; xv[2] = xa.z; xv[3] = xa.w;
        if (RPT == 8) {
            const float4 xb = *(const float4*)&Xt[k * RPAD + r0p + 4];
            xv[4] = xb.x; xv[5] = xb.y; xv[6] = xb.z; xv[7] = xb.w;
        }
        const float4 wa = *(const float4*)&Ws[k * OUTC + c0];
        const float wv[4] = {wa.x, wa.y, wa.z, wa.w};
#pragma unroll
        for (int i = 0; i < RPT; i++)
#pragma unroll
            for (int j = 0; j < 4; j++)
                acc[i][j] += xv[i] * wv[j];
    }

    float4 bv = make_float4(0.f, 0.f, 0.f, 0.f);
    if (BIAS) bv = *(const float4*)&bias[c0];
#pragma unroll
    for (int i = 0; i < RPT; i++) {
        const int row = row0 + r0 + i;
        if (row < N) {
            const float sc = SCALE ? dinv[row] : 1.f;
            float4 o = make_float4(acc[i][0] * sc + bv.x, acc[i][1] * sc + bv.y,
                                   acc[i][2] * sc + bv.z, acc[i][3] * sc + bv.w);
            *(float4*)&Y[(long)row * OUTC + c0] = o;
        }
    }
}

// out[i] = relu( dinv_i * (sum_e T'[src_e] + T'[i]) + b ),  T' pre-scaled by dinv_row.
// 16 lanes/node, float4/lane. 8 gathers in flight, pipelined index loads.
template <bool RELU>
__global__ __launch_bounds__(256) void agg_kernel(const float* __restrict__ T,
                                                  const int* __restrict__ offs,
                                                  const int* __restrict__ csr_src,
                                                  const float* __restrict__ dinv,
                                                  const float* __restrict__ bias,
                                                  float* __restrict__ Y, int N) {
    const int tid = threadIdx.x;
    const int node = blockIdx.x * 16 + (tid >> 4);
    const int l16 = tid & 15;
    if (node >= N) return;

    const int start = offs[node];
    const int n_edges = offs[node + 1] - start;
    const int* ep = csr_src + start;
    const int fo = l16 * 4;

    float4 acc = make_float4(0.f, 0.f, 0.f, 0.f);

    int s[8];
    int e = 0;
    if (n_edges >= 8) {
#pragma unroll
        for (int j = 0; j < 8; j++) s[j] = ep[j];
        while (true) {
            float4 h[8];
#pragma unroll
            for (int j = 0; j < 8; j++)
                h[j] = *(const float4*)&T[(long)s[j] * 64 + fo];
            const int next = e + 8;
            const bool more = (next + 8 <= n_edges);
            if (more) {
#pragma unroll
                for (int j = 0; j < 8; j++) s[j] = ep[next + j];
            }
#pragma unroll
            for (int j = 0; j < 8; j++) {
                acc.x += h[j].x;
                acc.y += h[j].y;
                acc.z += h[j].z;
                acc.w += h[j].w;
            }
            e = next;
            if (!more) break;
        }
    }
    if (e + 4 <= n_edges) {
        int s4[4];
#pragma unroll
        for (int j = 0; j < 4; j++) s4[j] = ep[e + j];
        float4 h[4];
#pragma unroll
        for (int j = 0; j < 4; j++)
            h[j] = *(const float4*)&T[(long)s4[j] * 64 + fo];
#pragma unroll
        for (int j = 0; j < 4; j++) {
            acc.x += h[j].x;
            acc.y += h[j].y;
            acc.z += h[j].z;
            acc.w += h[j].w;
        }
        e += 4;
    }
    for (; e < n_edges; e++) {
        const float4 hv = *(const float4*)&T[(long)ep[e] * 64 + fo];
        acc.x += hv.x;
        acc.y += hv.y;
        acc.z += hv.z;
        acc.w += hv.w;
    }

    const float di = dinv[node];
    const float4 self = *(const float4*)&T[(long)node * 64 + fo];
    const float4 b4 = *(const float4*)&bias[fo];
    float4 o;
    o.x = di * (acc.x + self.x) + b4.x;
    o.y = di * (acc.y + self.y) + b4.y;
    o.z = di * (acc.z + self.z) + b4.z;
    o.w = di * (acc.w + self.w) + b4.w;
    if (RELU) {
        o.x = fmaxf(o.x, 0.f);
        o.y = fmaxf(o.y, 0.f);
        o.z = fmaxf(o.z, 0.f);
        o.w = fmaxf(o.w, 0.f);
    }
    *(float4*)&Y[(long)node * 64 + fo] = o;
}

extern "C" void kernel_launch(void* const* d_in, const int* in_sizes, int n_in,
                              void* d_out, int out_size, void* d_ws, size_t ws_size,
                              hipStream_t stream) {
    const float* x  = (const float*)d_in[0];
    const int*   ei = (const int*)d_in[1];
    const float* W1 = (const float*)d_in[2];
    const float* b1 = (const float*)d_in[3];
    const float* W2 = (const float*)d_in[4];
    const float* b2 = (const float*)d_in[5];
    const float* Wf = (const float*)d_in[6];
    const float* bf = (const float*)d_in[7];

    const int N = in_sizes[0] / 64;
    const int E = in_sizes[1] / 2;
    const int* src = ei;
    const int* dst = ei + E;
    const int K1 = (N + NODES_PER_BKT - 1) / NODES_PER_BKT;

    char* ws = (char*)d_ws;
    size_t off = 0;
    auto alloc = [&](size_t bytes) -> void* {
        void* p = ws + off;
        off = (off + bytes + 255) & ~(size_t)255;
        return p;
    };
    int*   bkt_cnt    = (int*)alloc(256 * 4);
    int*   bkt_start  = (int*)alloc(257 * 4);
    int*   bkt_cursor = (int*)alloc(256 * 4);
    float* dinv       = (float*)alloc((size_t)N * 4);
    int*   offs       = (int*)alloc((size_t)(N + 1) * 4);
    int*   csr_src    = (int*)alloc((size_t)E * 4);
    float* A          = (float*)alloc((size_t)N * 64 * 4);
    float* B          = (float*)alloc((size_t)N * 64 * 4);
    int2*  staging    = (int2*)A;  // dead before gemm1 writes A

    const int NB = 256;
    const int CHK = (E + NB - 1) / NB;

    // ---- CSR build: counting sort, no random scatter ----
    hipMemsetAsync(bkt_cnt, 0, (size_t)K1 * 4, stream);
    coarse_hist_kernel<<<NB, 256, 0, stream>>>(dst, E, bkt_cnt, K1, CHK);
    bucket_scan_kernel<<<1, 64, 0, stream>>>(bkt_cnt, bkt_start, bkt_cursor, K1, E);
    partition_kernel<<<NB, 256, 0, stream>>>(src, dst, E, bkt_cursor, staging, K1, CHK);
    bucket_build_kernel<<<K1, 512, 0, stream>>>(staging, bkt_start, dinv, offs, csr_src, N, E);

    // ---- layer 1 ----
    gemm_kernel<64, 8, false, true><<<(N + 127) / 128, 256, 0, stream>>>(x, W1, nullptr, dinv, A, N);
    agg_kernel<true><<<(N + 15) / 16, 256, 0, stream>>>(A, offs, csr_src, dinv, b1, B, N);

    // ---- layer 2 ----
    gemm_kernel<64, 8, false, true><<<(N + 127) / 128, 256, 0, stream>>>(B, W2, nullptr, dinv, A, N);
    agg_kernel<true><<<(N + 15) / 16, 256, 0, stream>>>(A, offs, csr_src, dinv, b2, B, N);

    // ---- head ----
    gemm_kernel<32, 4, true, false><<<(N + 127) / 128, 256, 0, stream>>>(B, Wf, bf, nullptr, (float*)d_out, N);
}

// Round 7
// 256.551 us; speedup vs baseline: 1.3077x; 1.2117x over previous
//
#include <hip/hip_runtime.h>

// ---------------------------------------------------------------------------
// 2-layer GCN + linear head on MI355X.
// R3: counting-sort CSR build. R4: pipelined gather agg. R6: reg-blocked gemm.
// R7: T' gather table stored as bf16 (RNE) -> agg's structural HBM traffic
//     halves (each XCD streams the whole table: 8 x 25.6MB fp32 -> 8 x 12.8MB).
//     agg regrouped to 8 lanes/node x 16B (uint4 = 8 bf16). Build: hist writes
//     per-block partials (no memset, no global atomics); int4 edge reads.
// ---------------------------------------------------------------------------

#define NODE_SHIFT 9
#define NODES_PER_BKT 512
#define K1PAD 208
#define NB_PART 256

__device__ __forceinline__ unsigned short f2bf_rne(float f) {
    unsigned int u = __float_as_uint(f);
    unsigned int r = (u + 0x7FFFu + ((u >> 16) & 1u)) >> 16;
    return (unsigned short)r;
}
__device__ __forceinline__ float bf_lo(unsigned int u) {
    return __uint_as_float(u << 16);
}
__device__ __forceinline__ float bf_hi(unsigned int u) {
    return __uint_as_float(u & 0xFFFF0000u);
}

// Per-block LDS histogram of dst>>NODE_SHIFT -> PARTIAL counts (plain stores).
__global__ __launch_bounds__(256) void coarse_hist_kernel(const int* __restrict__ dst, int E,
                                                          int* __restrict__ bkt_partial,
                                                          int K1, int CHK) {
    __shared__ int lcnt[256];
    const int tid = threadIdx.x;
    const int start = blockIdx.x * CHK;
    const int end = min(E, start + CHK);
    for (int k = tid; k < 256; k += 256) lcnt[k] = 0;
    __syncthreads();
    const int s4 = start >> 2;
    const int e4 = end >> 2;  // CHK multiple of 4; E%4==0
    for (int i = s4 + tid; i < e4; i += 256) {
        const int4 d = ((const int4*)dst)[i];
        atomicAdd(&lcnt[d.x >> NODE_SHIFT], 1);
        atomicAdd(&lcnt[d.y >> NODE_SHIFT], 1);
        atomicAdd(&lcnt[d.z >> NODE_SHIFT], 1);
        atomicAdd(&lcnt[d.w >> NODE_SHIFT], 1);
    }
    __syncthreads();
    for (int k = tid; k < K1; k += 256)
        bkt_partial[blockIdx.x * K1PAD + k] = lcnt[k];
}

// One block: reduce partials per bucket, exclusive scan, write start+cursor.
__global__ __launch_bounds__(256) void bucket_scan_kernel(const int* __restrict__ bkt_partial,
                                                          int* __restrict__ bkt_start,
                                                          int* __restrict__ bkt_cursor,
                                                          int K1, int E) {
    __shared__ int wsum[4];
    const int tid = threadIdx.x;
    const int lane = tid & 63;
    const int wave = tid >> 6;
    int c = 0;
    if (tid < K1)
        for (int b = 0; b < NB_PART; b++) c += bkt_partial[b * K1PAD + tid];
    int inc = c;
#pragma unroll
    for (int o = 1; o < 64; o <<= 1) {
        int t = __shfl_up(inc, o, 64);
        if (lane >= o) inc += t;
    }
    if (lane == 63) wsum[wave] = inc;
    __syncthreads();
    int wpre = 0;
#pragma unroll
    for (int w = 0; w < 4; w++) wpre += (w < wave) ? wsum[w] : 0;
    const int p = wpre + inc - c;
    if (tid < K1) { bkt_start[tid] = p; bkt_cursor[tid] = p; }
    if (tid == 0) bkt_start[K1] = E;
}

// Partition edges into coarse buckets: LDS hist -> range reservation -> write.
__global__ __launch_bounds__(256) void partition_kernel(const int* __restrict__ src,
                                                        const int* __restrict__ dst, int E,
                                                        int* __restrict__ bkt_cursor,
                                                        int2* __restrict__ staging,
                                                        int K1, int CHK) {
    __shared__ int lcnt[256];
    __shared__ int lcur[256];
    const int tid = threadIdx.x;
    const int start = blockIdx.x * CHK;
    const int end = min(E, start + CHK);
    for (int k = tid; k < 256; k += 256) lcnt[k] = 0;
    __syncthreads();
    const int s4 = start >> 2;
    const int e4 = end >> 2;
    for (int i = s4 + tid; i < e4; i += 256) {
        const int4 d = ((const int4*)dst)[i];
        atomicAdd(&lcnt[d.x >> NODE_SHIFT], 1);
        atomicAdd(&lcnt[d.y >> NODE_SHIFT], 1);
        atomicAdd(&lcnt[d.z >> NODE_SHIFT], 1);
        atomicAdd(&lcnt[d.w >> NODE_SHIFT], 1);
    }
    __syncthreads();
    for (int k = tid; k < K1; k += 256) {
        int cc = lcnt[k];
        lcur[k] = cc ? atomicAdd(&bkt_cursor[k], cc) : 0;
    }
    __syncthreads();
    for (int i = s4 + tid; i < e4; i += 256) {
        const int4 d = ((const int4*)dst)[i];
        const int4 s = ((const int4*)src)[i];
        int pos;
        pos = atomicAdd(&lcur[d.x >> NODE_SHIFT], 1); staging[pos] = make_int2(d.x, s.x);
        pos = atomicAdd(&lcur[d.y >> NODE_SHIFT], 1); staging[pos] = make_int2(d.y, s.y);
        pos = atomicAdd(&lcur[d.z >> NODE_SHIFT], 1); staging[pos] = make_int2(d.z, s.z);
        pos = atomicAdd(&lcur[d.w >> NODE_SHIFT], 1); staging[pos] = make_int2(d.w, s.w);
    }
}

// One 512-thr block per bucket: LDS degree count -> scan -> offs/dinv -> CSR.
__global__ __launch_bounds__(512) void bucket_build_kernel(const int2* __restrict__ staging,
                                                           const int* __restrict__ bkt_start,
                                                           float* __restrict__ dinv,
                                                           int* __restrict__ offs,
                                                           int* __restrict__ csr_src,
                                                           int N, int E) {
    __shared__ int cnt[NODES_PER_BKT];
    __shared__ int wsum[8];
    const int tid = threadIdx.x;
    const int node0 = blockIdx.x * NODES_PER_BKT;
    const int estart = bkt_start[blockIdx.x];
    const int eend = bkt_start[blockIdx.x + 1];

    cnt[tid] = 0;
    __syncthreads();
    for (int e = estart + tid; e < eend; e += 512)
        atomicAdd(&cnt[staging[e].x - node0], 1);
    __syncthreads();

    const int lane = tid & 63;
    const int wave = tid >> 6;
    const int c = cnt[tid];
    int inc = c;
#pragma unroll
    for (int o = 1; o < 64; o <<= 1) {
        int t = __shfl_up(inc, o, 64);
        if (lane >= o) inc += t;
    }
    if (lane == 63) wsum[wave] = inc;
    __syncthreads();
    int wpre = 0;
#pragma unroll
    for (int w = 0; w < 8; w++) wpre += (w < wave) ? wsum[w] : 0;
    const int p = estart + wpre + inc - c;

    const int node = node0 + tid;
    __syncthreads();  // cnt reuse as cursor
    if (node < N) {
        offs[node] = p;
        dinv[node] = rsqrtf((float)c + 1.0f);
    }
    cnt[tid] = p;
    __syncthreads();
    for (int e = estart + tid; e < eend; e += 512) {
        int2 r = staging[e];
        int pos = atomicAdd(&cnt[r.x - node0], 1);
        csr_src[pos] = r.y;
    }
    if (blockIdx.x == 0 && tid == 0) offs[N] = E;
}

// Y[N,OUTC] = (X[N,64] @ W[64,OUTC]) * (SCALE ? dinv[row] : 1) (+ bias)
// 256 thr/block, RPT rows x 4 cols per thread, X transposed in LDS, padded.
// BF16OUT: store RNE-rounded bf16 (ushort4 per thread).
template <int OUTC, int RPT, bool BIAS, bool SCALE, bool BF16OUT>
__global__ __launch_bounds__(256) void gemm_kernel(const float* __restrict__ X,
                                                   const float* __restrict__ W,
                                                   const float* __restrict__ bias,
                                                   const float* __restrict__ dinv,
                                                   void* __restrict__ Yv, int N) {
    constexpr int CG = OUTC / 4;
    constexpr int RG = 256 / CG;
    constexpr int R = RG * RPT;          // 128 for both configs
    constexpr int RPAD = R + (R / 32) * 4;
    __shared__ float Ws[64 * OUTC];
    __shared__ float Xt[64 * RPAD];

    const int tid = threadIdx.x;
    const int row0 = blockIdx.x * R;

    for (int l = tid; l < 64 * OUTC / 4; l += 256)
        ((float4*)Ws)[l] = ((const float4*)W)[l];

    for (int l = tid; l < R * 16; l += 256) {
        const int r = l & (R - 1);
        const int kq = l >> 7;  // R == 128
        float4 v = make_float4(0.f, 0.f, 0.f, 0.f);
        const int row = row0 + r;
        if (row < N) v = ((const float4*)(X + (long)row * 64))[kq];
        const int rp = r + (r >> 5) * 4;
        Xt[(4 * kq + 0) * RPAD + rp] = v.x;
        Xt[(4 * kq + 1) * RPAD + rp] = v.y;
        Xt[(4 * kq + 2) * RPAD + rp] = v.z;
        Xt[(4 * kq + 3) * RPAD + rp] = v.w;
    }
    __syncthreads();

    const int cg = tid % CG;
    const int rg = tid / CG;
    const int c0 = cg * 4;
    const int r0 = rg * RPT;
    const int r0p = r0 + (r0 >> 5) * 4;

    float acc[RPT][4];
#pragma unroll
    for (int i = 0; i < RPT; i++)
#pragma unroll
        for (int j = 0; j < 4; j++) acc[i][j] = 0.f;

#pragma unroll 4
    for (int k = 0; k < 64; k++) {
        float xv[RPT];
        const float4 xa = *(const float4*)&Xt[k * RPAD + r0p];
        xv[0] = xa.x; xv[1] = xa.y; xv[2] = xa.z; xv[3] = xa.w;
        if (RPT == 8) {
            const float4 xb = *(const float4*)&Xt[k * RPAD + r0p + 4];
            xv[4] = xb.x; xv[5] = xb.y; xv[6] = xb.z; xv[7] = xb.w;
        }
        const float4 wa = *(const float4*)&Ws[k * OUTC + c0];
        const float wv[4] = {wa.x, wa.y, wa.z, wa.w};
#pragma unroll
        for (int i = 0; i < RPT; i++)
#pragma unroll
            for (int j = 0; j < 4; j++)
                acc[i][j] += xv[i] * wv[j];
    }

    float4 bv = make_float4(0.f, 0.f, 0.f, 0.f);
    if (BIAS) bv = *(const float4*)&bias[c0];
#pragma unroll
    for (int i = 0; i < RPT; i++) {
        const int row = row0 + r0 + i;
        if (row < N) {
            const float sc = SCALE ? dinv[row] : 1.f;
            float4 o = make_float4(acc[i][0] * sc + bv.x, acc[i][1] * sc + bv.y,
                                   acc[i][2] * sc + bv.z, acc[i][3] * sc + bv.w);
            if (BF16OUT) {
                ushort4 o16;
                o16.x = f2bf_rne(o.x);
                o16.y = f2bf_rne(o.y);
                o16.z = f2bf_rne(o.z);
                o16.w = f2bf_rne(o.w);
                *(ushort4*)&((unsigned short*)Yv)[(long)row * OUTC + c0] = o16;
            } else {
                *(float4*)&((float*)Yv)[(long)row * OUTC + c0] = o;
            }
        }
    }
}

// out[i] = relu( dinv_i * (sum_e T'[src_e] + T'[i]) + b ),  T' bf16, pre-scaled.
// 8 lanes/node (16B = 8 bf16 per lane), 32 nodes per 256-thr block.
// 8 gathers in flight, pipelined index loads. Output fp32.
template <bool RELU>
__global__ __launch_bounds__(256) void agg_kernel(const unsigned short* __restrict__ T,
                                                  const int* __restrict__ offs,
                                                  const int* __restrict__ csr_src,
                                                  const float* __restrict__ dinv,
                                                  const float* __restrict__ bias,
                                                  float* __restrict__ Y, int N) {
    const int tid = threadIdx.x;
    const int node = blockIdx.x * 32 + (tid >> 3);
    const int l8 = tid & 7;
    if (node >= N) return;

    const int start = offs[node];
    const int n_edges = offs[node + 1] - start;
    const int* ep = csr_src + start;
    const int fo = l8 * 8;  // ushort offset within 64-elem row

    float acc[8];
#pragma unroll
    for (int j = 0; j < 8; j++) acc[j] = 0.f;

#define ACC_U4(v)                                   \
    do {                                            \
        acc[0] += bf_lo((v).x); acc[1] += bf_hi((v).x); \
        acc[2] += bf_lo((v).y); acc[3] += bf_hi((v).y); \
        acc[4] += bf_lo((v).z); acc[5] += bf_hi((v).z); \
        acc[6] += bf_lo((v).w); acc[7] += bf_hi((v).w); \
    } while (0)

    int s[8];
    int e = 0;
    if (n_edges >= 8) {
#pragma unroll
        for (int j = 0; j < 8; j++) s[j] = ep[j];
        while (true) {
            uint4 h[8];
#pragma unroll
            for (int j = 0; j < 8; j++)
                h[j] = *(const uint4*)&T[(long)s[j] * 64 + fo];
            const int next = e + 8;
            const bool more = (next + 8 <= n_edges);
            if (more) {
#pragma unroll
                for (int j = 0; j < 8; j++) s[j] = ep[next + j];
            }
#pragma unroll
            for (int j = 0; j < 8; j++) ACC_U4(h[j]);
            e = next;
            if (!more) break;
        }
    }
    if (e + 4 <= n_edges) {
        int s4[4];
#pragma unroll
        for (int j = 0; j < 4; j++) s4[j] = ep[e + j];
        uint4 h[4];
#pragma unroll
        for (int j = 0; j < 4; j++)
            h[j] = *(const uint4*)&T[(long)s4[j] * 64 + fo];
#pragma unroll
        for (int j = 0; j < 4; j++) ACC_U4(h[j]);
        e += 4;
    }
    for (; e < n_edges; e++) {
        const uint4 hv = *(const uint4*)&T[(long)ep[e] * 64 + fo];
        ACC_U4(hv);
    }
#undef ACC_U4

    const float di = dinv[node];
    const uint4 sv = *(const uint4*)&T[(long)node * 64 + fo];
    float self[8] = {bf_lo(sv.x), bf_hi(sv.x), bf_lo(sv.y), bf_hi(sv.y),
                     bf_lo(sv.z), bf_hi(sv.z), bf_lo(sv.w), bf_hi(sv.w)};
    const float4 ba = *(const float4*)&bias[l8 * 8];
    const float4 bb = *(const float4*)&bias[l8 * 8 + 4];
    const float bv[8] = {ba.x, ba.y, ba.z, ba.w, bb.x, bb.y, bb.z, bb.w};
    float o[8];
#pragma unroll
    for (int j = 0; j < 8; j++) {
        o[j] = di * (acc[j] + self[j]) + bv[j];
        if (RELU) o[j] = fmaxf(o[j], 0.f);
    }
    float* yp = &Y[(long)node * 64 + l8 * 8];
    *(float4*)yp = make_float4(o[0], o[1], o[2], o[3]);
    *(float4*)(yp + 4) = make_float4(o[4], o[5], o[6], o[7]);
}

extern "C" void kernel_launch(void* const* d_in, const int* in_sizes, int n_in,
                              void* d_out, int out_size, void* d_ws, size_t ws_size,
                              hipStream_t stream) {
    const float* x  = (const float*)d_in[0];
    const int*   ei = (const int*)d_in[1];
    const float* W1 = (const float*)d_in[2];
    const float* b1 = (const float*)d_in[3];
    const float* W2 = (const float*)d_in[4];
    const float* b2 = (const float*)d_in[5];
    const float* Wf = (const float*)d_in[6];
    const float* bf = (const float*)d_in[7];

    const int N = in_sizes[0] / 64;
    const int E = in_sizes[1] / 2;
    const int* src = ei;
    const int* dst = ei + E;
    const int K1 = (N + NODES_PER_BKT - 1) / NODES_PER_BKT;

    char* ws = (char*)d_ws;
    size_t off = 0;
    auto alloc = [&](size_t bytes) -> void* {
        void* p = ws + off;
        off = (off + bytes + 255) & ~(size_t)255;
        return p;
    };
    int*   bkt_partial = (int*)alloc((size_t)NB_PART * K1PAD * 4);
    int*   bkt_start   = (int*)alloc(257 * 4);
    int*   bkt_cursor  = (int*)alloc(256 * 4);
    float* dinv        = (float*)alloc((size_t)N * 4);
    int*   offs        = (int*)alloc((size_t)(N + 1) * 4);
    int*   csr_src     = (int*)alloc((size_t)E * 4);
    unsigned short* A  = (unsigned short*)alloc((size_t)N * 64 * 2);  // bf16 T'
    float* B           = (float*)alloc((size_t)N * 64 * 4);
    int2*  staging     = (int2*)alloc((size_t)E * 8);  // keep separate from A

    const int NB = NB_PART;
    const int CHK = ((E / 4 + NB - 1) / NB) * 4;  // per-block chunk, multiple of 4

    // ---- CSR build: counting sort, no random scatter, no memset ----
    coarse_hist_kernel<<<NB, 256, 0, stream>>>(dst, E, bkt_partial, K1, CHK);
    bucket_scan_kernel<<<1, 256, 0, stream>>>(bkt_partial, bkt_start, bkt_cursor, K1, E);
    partition_kernel<<<NB, 256, 0, stream>>>(src, dst, E, bkt_cursor, staging, K1, CHK);
    bucket_build_kernel<<<K1, 512, 0, stream>>>(staging, bkt_start, dinv, offs, csr_src, N, E);

    // ---- layer 1: A = bf16(dinv*(x@W1)) ; B = relu(dinv*(agg+self)+b1) ----
    gemm_kernel<64, 8, false, true, true><<<(N + 127) / 128, 256, 0, stream>>>(x, W1, nullptr, dinv, A, N);
    agg_kernel<true><<<(N + 31) / 32, 256, 0, stream>>>(A, offs, csr_src, dinv, b1, B, N);

    // ---- layer 2 ----
    gemm_kernel<64, 8, false, true, true><<<(N + 127) / 128, 256, 0, stream>>>(B, W2, nullptr, dinv, A, N);
    agg_kernel<true><<<(N + 31) / 32, 256, 0, stream>>>(A, offs, csr_src, dinv, b2, B, N);

    // ---- head: out = B@Wf + bf (fp32) ----
    gemm_kernel<32, 4, true, false, false><<<(N + 127) / 128, 256, 0, stream>>>(B, Wf, bf, nullptr, d_out, N);
}

// Round 8
// 230.122 us; speedup vs baseline: 1.4579x; 1.1148x over previous
//
#include <hip/hip_runtime.h>

// ---------------------------------------------------------------------------
// 2-layer GCN + linear head on MI355X.
// R3: counting-sort CSR build. R4: pipelined gather agg. R6: reg-blocked gemm.
// R7: bf16 gather table (halves structural per-XCD stream of T').
// R8: agg+gemm FUSED: phase1 gathers h for 32 nodes into LDS (fp32, identical
//     math), phase2 mini-GEMM h@W from LDS -> bf16 T' / fp32 head output.
//     Eliminates the 25.6MB fp32 B buffer round-trip entirely (x2 layers).
// ---------------------------------------------------------------------------

#define NODE_SHIFT 9
#define NODES_PER_BKT 512
#define K1PAD 208
#define NB_PART 256
#define HPAD 68

__device__ __forceinline__ unsigned short f2bf_rne(float f) {
    unsigned int u = __float_as_uint(f);
    unsigned int r = (u + 0x7FFFu + ((u >> 16) & 1u)) >> 16;
    return (unsigned short)r;
}
__device__ __forceinline__ float bf_lo(unsigned int u) {
    return __uint_as_float(u << 16);
}
__device__ __forceinline__ float bf_hi(unsigned int u) {
    return __uint_as_float(u & 0xFFFF0000u);
}

// Per-block LDS histogram of dst>>NODE_SHIFT -> PARTIAL counts (plain stores).
__global__ __launch_bounds__(256) void coarse_hist_kernel(const int* __restrict__ dst, int E,
                                                          int* __restrict__ bkt_partial,
                                                          int K1, int CHK) {
    __shared__ int lcnt[256];
    const int tid = threadIdx.x;
    const int start = blockIdx.x * CHK;
    const int end = min(E, start + CHK);
    for (int k = tid; k < 256; k += 256) lcnt[k] = 0;
    __syncthreads();
    const int s4 = start >> 2;
    const int e4 = end >> 2;  // CHK multiple of 4; E%4==0
    for (int i = s4 + tid; i < e4; i += 256) {
        const int4 d = ((const int4*)dst)[i];
        atomicAdd(&lcnt[d.x >> NODE_SHIFT], 1);
        atomicAdd(&lcnt[d.y >> NODE_SHIFT], 1);
        atomicAdd(&lcnt[d.z >> NODE_SHIFT], 1);
        atomicAdd(&lcnt[d.w >> NODE_SHIFT], 1);
    }
    __syncthreads();
    for (int k = tid; k < K1; k += 256)
        bkt_partial[blockIdx.x * K1PAD + k] = lcnt[k];
}

// One block: reduce partials per bucket, exclusive scan, write start+cursor.
__global__ __launch_bounds__(256) void bucket_scan_kernel(const int* __restrict__ bkt_partial,
                                                          int* __restrict__ bkt_start,
                                                          int* __restrict__ bkt_cursor,
                                                          int K1, int E) {
    __shared__ int wsum[4];
    const int tid = threadIdx.x;
    const int lane = tid & 63;
    const int wave = tid >> 6;
    int c = 0;
    if (tid < K1)
        for (int b = 0; b < NB_PART; b++) c += bkt_partial[b * K1PAD + tid];
    int inc = c;
#pragma unroll
    for (int o = 1; o < 64; o <<= 1) {
        int t = __shfl_up(inc, o, 64);
        if (lane >= o) inc += t;
    }
    if (lane == 63) wsum[wave] = inc;
    __syncthreads();
    int wpre = 0;
#pragma unroll
    for (int w = 0; w < 4; w++) wpre += (w < wave) ? wsum[w] : 0;
    const int p = wpre + inc - c;
    if (tid < K1) { bkt_start[tid] = p; bkt_cursor[tid] = p; }
    if (tid == 0) bkt_start[K1] = E;
}

// Partition edges into coarse buckets: LDS hist -> range reservation -> write.
__global__ __launch_bounds__(256) void partition_kernel(const int* __restrict__ src,
                                                        const int* __restrict__ dst, int E,
                                                        int* __restrict__ bkt_cursor,
                                                        int2* __restrict__ staging,
                                                        int K1, int CHK) {
    __shared__ int lcnt[256];
    __shared__ int lcur[256];
    const int tid = threadIdx.x;
    const int start = blockIdx.x * CHK;
    const int end = min(E, start + CHK);
    for (int k = tid; k < 256; k += 256) lcnt[k] = 0;
    __syncthreads();
    const int s4 = start >> 2;
    const int e4 = end >> 2;
    for (int i = s4 + tid; i < e4; i += 256) {
        const int4 d = ((const int4*)dst)[i];
        atomicAdd(&lcnt[d.x >> NODE_SHIFT], 1);
        atomicAdd(&lcnt[d.y >> NODE_SHIFT], 1);
        atomicAdd(&lcnt[d.z >> NODE_SHIFT], 1);
        atomicAdd(&lcnt[d.w >> NODE_SHIFT], 1);
    }
    __syncthreads();
    for (int k = tid; k < K1; k += 256) {
        int cc = lcnt[k];
        lcur[k] = cc ? atomicAdd(&bkt_cursor[k], cc) : 0;
    }
    __syncthreads();
    for (int i = s4 + tid; i < e4; i += 256) {
        const int4 d = ((const int4*)dst)[i];
        const int4 s = ((const int4*)src)[i];
        int pos;
        pos = atomicAdd(&lcur[d.x >> NODE_SHIFT], 1); staging[pos] = make_int2(d.x, s.x);
        pos = atomicAdd(&lcur[d.y >> NODE_SHIFT], 1); staging[pos] = make_int2(d.y, s.y);
        pos = atomicAdd(&lcur[d.z >> NODE_SHIFT], 1); staging[pos] = make_int2(d.z, s.z);
        pos = atomicAdd(&lcur[d.w >> NODE_SHIFT], 1); staging[pos] = make_int2(d.w, s.w);
    }
}

// One 512-thr block per bucket: LDS degree count -> scan -> offs/dinv -> CSR.
__global__ __launch_bounds__(512) void bucket_build_kernel(const int2* __restrict__ staging,
                                                           const int* __restrict__ bkt_start,
                                                           float* __restrict__ dinv,
                                                           int* __restrict__ offs,
                                                           int* __restrict__ csr_src,
                                                           int N, int E) {
    __shared__ int cnt[NODES_PER_BKT];
    __shared__ int wsum[8];
    const int tid = threadIdx.x;
    const int node0 = blockIdx.x * NODES_PER_BKT;
    const int estart = bkt_start[blockIdx.x];
    const int eend = bkt_start[blockIdx.x + 1];

    cnt[tid] = 0;
    __syncthreads();
    for (int e = estart + tid; e < eend; e += 512)
        atomicAdd(&cnt[staging[e].x - node0], 1);
    __syncthreads();

    const int lane = tid & 63;
    const int wave = tid >> 6;
    const int c = cnt[tid];
    int inc = c;
#pragma unroll
    for (int o = 1; o < 64; o <<= 1) {
        int t = __shfl_up(inc, o, 64);
        if (lane >= o) inc += t;
    }
    if (lane == 63) wsum[wave] = inc;
    __syncthreads();
    int wpre = 0;
#pragma unroll
    for (int w = 0; w < 8; w++) wpre += (w < wave) ? wsum[w] : 0;
    const int p = estart + wpre + inc - c;

    const int node = node0 + tid;
    __syncthreads();  // cnt reuse as cursor
    if (node < N) {
        offs[node] = p;
        dinv[node] = rsqrtf((float)c + 1.0f);
    }
    cnt[tid] = p;
    __syncthreads();
    for (int e = estart + tid; e < eend; e += 512) {
        int2 r = staging[e];
        int pos = atomicAdd(&cnt[r.x - node0], 1);
        csr_src[pos] = r.y;
    }
    if (blockIdx.x == 0 && tid == 0) offs[N] = E;
}

// gemm1: Y[N,64] = bf16( dinv[row] * (X[N,64] @ W[64,64]) )
__global__ __launch_bounds__(256) void gemm1_kernel(const float* __restrict__ X,
                                                    const float* __restrict__ W,
                                                    const float* __restrict__ dinv,
                                                    unsigned short* __restrict__ Y, int N) {
    constexpr int OUTC = 64, RPT = 8;
    constexpr int R = 128;
    constexpr int RPAD = R + (R / 32) * 4;
    __shared__ float Ws[64 * OUTC];
    __shared__ float Xt[64 * RPAD];

    const int tid = threadIdx.x;
    const int row0 = blockIdx.x * R;

    for (int l = tid; l < 64 * OUTC / 4; l += 256)
        ((float4*)Ws)[l] = ((const float4*)W)[l];

    for (int l = tid; l < R * 16; l += 256) {
        const int r = l & (R - 1);
        const int kq = l >> 7;
        float4 v = make_float4(0.f, 0.f, 0.f, 0.f);
        const int row = row0 + r;
        if (row < N) v = ((const float4*)(X + (long)row * 64))[kq];
        const int rp = r + (r >> 5) * 4;
        Xt[(4 * kq + 0) * RPAD + rp] = v.x;
        Xt[(4 * kq + 1) * RPAD + rp] = v.y;
        Xt[(4 * kq + 2) * RPAD + rp] = v.z;
        Xt[(4 * kq + 3) * RPAD + rp] = v.w;
    }
    __syncthreads();

    const int cg = tid % 16;
    const int rg = tid / 16;
    const int c0 = cg * 4;
    const int r0 = rg * RPT;
    const int r0p = r0 + (r0 >> 5) * 4;

    float acc[RPT][4];
#pragma unroll
    for (int i = 0; i < RPT; i++)
#pragma unroll
        for (int j = 0; j < 4; j++) acc[i][j] = 0.f;

#pragma unroll 4
    for (int k = 0; k < 64; k++) {
        float xv[RPT];
        const float4 xa = *(const float4*)&Xt[k * RPAD + r0p];
        const float4 xb = *(const float4*)&Xt[k * RPAD + r0p + 4];
        xv[0] = xa.x; xv[1] = xa.y; xv[2] = xa.z; xv[3] = xa.w;
        xv[4] = xb.x; xv[5] = xb.y; xv[6] = xb.z; xv[7] = xb.w;
        const float4 wa = *(const float4*)&Ws[k * OUTC + c0];
        const float wv[4] = {wa.x, wa.y, wa.z, wa.w};
#pragma unroll
        for (int i = 0; i < RPT; i++)
#pragma unroll
            for (int j = 0; j < 4; j++)
                acc[i][j] += xv[i] * wv[j];
    }

#pragma unroll
    for (int i = 0; i < RPT; i++) {
        const int row = row0 + r0 + i;
        if (row < N) {
            const float sc = dinv[row];
            ushort4 o16;
            o16.x = f2bf_rne(acc[i][0] * sc);
            o16.y = f2bf_rne(acc[i][1] * sc);
            o16.z = f2bf_rne(acc[i][2] * sc);
            o16.w = f2bf_rne(acc[i][3] * sc);
            *(ushort4*)&Y[(long)row * OUTC + c0] = o16;
        }
    }
}

// Fused agg+gemm. Phase 1: h = relu(dinv_i*(sum_e T[src]+T[i]) + ab) for 32
// nodes -> LDS (fp32, identical math to unfused). Phase 2: mini-GEMM
// h[32,64] @ W[64,OUTC]; HEAD: +bias, fp32 out; else: *dinv, bf16 out.
template <int OUTC, bool HEAD>
__global__ __launch_bounds__(256) void fused_agg_gemm_kernel(
    const unsigned short* __restrict__ T, const int* __restrict__ offs,
    const int* __restrict__ csr_src, const float* __restrict__ dinv,
    const float* __restrict__ aggbias, const float* __restrict__ W,
    const float* __restrict__ headbias, void* __restrict__ Yv, int N) {
    __shared__ float Ws[64 * OUTC];
    __shared__ float hs[32 * HPAD];

    const int tid = threadIdx.x;

    // stage W while phase-1 gathers are outstanding-independent
    for (int l = tid; l < 64 * OUTC / 4; l += 256)
        ((float4*)Ws)[l] = ((const float4*)W)[l];

    // ---- phase 1: aggregate 32 nodes, 8 lanes/node x 8 bf16 feats ----
    const int nl = tid >> 3;          // node_local 0..31
    const int node = blockIdx.x * 32 + nl;
    const int l8 = tid & 7;
    const int fo = l8 * 8;

    float o[8];
    if (node < N) {
        const int start = offs[node];
        const int n_edges = offs[node + 1] - start;
        const int* ep = csr_src + start;

        float acc[8];
#pragma unroll
        for (int j = 0; j < 8; j++) acc[j] = 0.f;

#define ACC_U4(v)                                       \
    do {                                                \
        acc[0] += bf_lo((v).x); acc[1] += bf_hi((v).x); \
        acc[2] += bf_lo((v).y); acc[3] += bf_hi((v).y); \
        acc[4] += bf_lo((v).z); acc[5] += bf_hi((v).z); \
        acc[6] += bf_lo((v).w); acc[7] += bf_hi((v).w); \
    } while (0)

        int s[8];
        int e = 0;
        if (n_edges >= 8) {
#pragma unroll
            for (int j = 0; j < 8; j++) s[j] = ep[j];
            while (true) {
                uint4 h[8];
#pragma unroll
                for (int j = 0; j < 8; j++)
                    h[j] = *(const uint4*)&T[(long)s[j] * 64 + fo];
                const int next = e + 8;
                const bool more = (next + 8 <= n_edges);
                if (more) {
#pragma unroll
                    for (int j = 0; j < 8; j++) s[j] = ep[next + j];
                }
#pragma unroll
                for (int j = 0; j < 8; j++) ACC_U4(h[j]);
                e = next;
                if (!more) break;
            }
        }
        if (e + 4 <= n_edges) {
            int s4[4];
#pragma unroll
            for (int j = 0; j < 4; j++) s4[j] = ep[e + j];
            uint4 h[4];
#pragma unroll
            for (int j = 0; j < 4; j++)
                h[j] = *(const uint4*)&T[(long)s4[j] * 64 + fo];
#pragma unroll
            for (int j = 0; j < 4; j++) ACC_U4(h[j]);
            e += 4;
        }
        for (; e < n_edges; e++) {
            const uint4 hv = *(const uint4*)&T[(long)ep[e] * 64 + fo];
            ACC_U4(hv);
        }
#undef ACC_U4

        const float di = dinv[node];
        const uint4 sv = *(const uint4*)&T[(long)node * 64 + fo];
        const float self[8] = {bf_lo(sv.x), bf_hi(sv.x), bf_lo(sv.y), bf_hi(sv.y),
                               bf_lo(sv.z), bf_hi(sv.z), bf_lo(sv.w), bf_hi(sv.w)};
        const float4 ba = *(const float4*)&aggbias[fo];
        const float4 bb = *(const float4*)&aggbias[fo + 4];
        const float bv[8] = {ba.x, ba.y, ba.z, ba.w, bb.x, bb.y, bb.z, bb.w};
#pragma unroll
        for (int j = 0; j < 8; j++)
            o[j] = fmaxf(di * (acc[j] + self[j]) + bv[j], 0.f);
    } else {
#pragma unroll
        for (int j = 0; j < 8; j++) o[j] = 0.f;
    }
    float* hp = &hs[nl * HPAD + fo];
    *(float4*)hp = make_float4(o[0], o[1], o[2], o[3]);
    *(float4*)(hp + 4) = make_float4(o[4], o[5], o[6], o[7]);
    __syncthreads();

    // ---- phase 2: h[32,64] @ W[64,OUTC] ----
    constexpr int CPT = OUTC / 8;    // cols per thread (8 for 64, 4 for 32)
    const int row = blockIdx.x * 32 + (tid >> 3);
    const int c0 = (tid & 7) * CPT;
    const int lrow = tid >> 3;

    float acc2[CPT];
#pragma unroll
    for (int j = 0; j < CPT; j++) acc2[j] = 0.f;

#pragma unroll 4
    for (int k = 0; k < 64; k++) {
        const float x = hs[lrow * HPAD + k];
        const float4 wa = *(const float4*)&Ws[k * OUTC + c0];
        acc2[0] += x * wa.x;
        acc2[1] += x * wa.y;
        acc2[2] += x * wa.z;
        acc2[3] += x * wa.w;
        if (CPT == 8) {
            const float4 wb = *(const float4*)&Ws[k * OUTC + c0 + 4];
            acc2[4] += x * wb.x;
            acc2[5] += x * wb.y;
            acc2[6] += x * wb.z;
            acc2[7] += x * wb.w;
        }
    }

    if (row < N) {
        if (HEAD) {
            const float4 hb = *(const float4*)&headbias[c0];
            float* yp = &((float*)Yv)[(long)row * OUTC + c0];
            *(float4*)yp = make_float4(acc2[0] + hb.x, acc2[1] + hb.y,
                                       acc2[2] + hb.z, acc2[3] + hb.w);
        } else {
            const float sc = dinv[row];
            unsigned short* yp = &((unsigned short*)Yv)[(long)row * OUTC + c0];
            ushort4 o0, o1;
            o0.x = f2bf_rne(acc2[0] * sc); o0.y = f2bf_rne(acc2[1] * sc);
            o0.z = f2bf_rne(acc2[2] * sc); o0.w = f2bf_rne(acc2[3] * sc);
            o1.x = f2bf_rne(acc2[4] * sc); o1.y = f2bf_rne(acc2[5] * sc);
            o1.z = f2bf_rne(acc2[6] * sc); o1.w = f2bf_rne(acc2[7] * sc);
            *(ushort4*)yp = o0;
            *(ushort4*)(yp + 4) = o1;
        }
    }
}

extern "C" void kernel_launch(void* const* d_in, const int* in_sizes, int n_in,
                              void* d_out, int out_size, void* d_ws, size_t ws_size,
                              hipStream_t stream) {
    const float* x  = (const float*)d_in[0];
    const int*   ei = (const int*)d_in[1];
    const float* W1 = (const float*)d_in[2];
    const float* b1 = (const float*)d_in[3];
    const float* W2 = (const float*)d_in[4];
    const float* b2 = (const float*)d_in[5];
    const float* Wf = (const float*)d_in[6];
    const float* bf = (const float*)d_in[7];

    const int N = in_sizes[0] / 64;
    const int E = in_sizes[1] / 2;
    const int* src = ei;
    const int* dst = ei + E;
    const int K1 = (N + NODES_PER_BKT - 1) / NODES_PER_BKT;

    char* ws = (char*)d_ws;
    size_t off = 0;
    auto alloc = [&](size_t bytes) -> void* {
        void* p = ws + off;
        off = (off + bytes + 255) & ~(size_t)255;
        return p;
    };
    int*   bkt_partial = (int*)alloc((size_t)NB_PART * K1PAD * 4);
    int*   bkt_start   = (int*)alloc(257 * 4);
    int*   bkt_cursor  = (int*)alloc(256 * 4);
    float* dinv        = (float*)alloc((size_t)N * 4);
    int*   offs        = (int*)alloc((size_t)(N + 1) * 4);
    int*   csr_src     = (int*)alloc((size_t)E * 4);
    unsigned short* A  = (unsigned short*)alloc((size_t)N * 64 * 2);  // T1' bf16
    unsigned short* A2 = (unsigned short*)alloc((size_t)N * 64 * 2);  // T2' bf16
    int2*  staging     = (int2*)alloc((size_t)E * 8);

    const int NB = NB_PART;
    const int CHK = ((E / 4 + NB - 1) / NB) * 4;

    // ---- CSR build: counting sort ----
    coarse_hist_kernel<<<NB, 256, 0, stream>>>(dst, E, bkt_partial, K1, CHK);
    bucket_scan_kernel<<<1, 256, 0, stream>>>(bkt_partial, bkt_start, bkt_cursor, K1, E);
    partition_kernel<<<NB, 256, 0, stream>>>(src, dst, E, bkt_cursor, staging, K1, CHK);
    bucket_build_kernel<<<K1, 512, 0, stream>>>(staging, bkt_start, dinv, offs, csr_src, N, E);

    // ---- layer 1 GEMM: A = bf16(dinv * (x@W1)) ----
    gemm1_kernel<<<(N + 127) / 128, 256, 0, stream>>>(x, W1, dinv, A, N);

    // ---- fused layer-1 agg + layer-2 GEMM: A2 = bf16(dinv * relu(...)@W2) ----
    fused_agg_gemm_kernel<64, false><<<(N + 31) / 32, 256, 0, stream>>>(
        A, offs, csr_src, dinv, b1, W2, nullptr, A2, N);

    // ---- fused layer-2 agg + head: out = relu(...)@Wf + bf ----
    fused_agg_gemm_kernel<32, true><<<(N + 31) / 32, 256, 0, stream>>>(
        A2, offs, csr_src, dinv, b2, Wf, bf, d_out, N);
}